// Round 5
// baseline (240.179 us; speedup 1.0000x reference)
//
#include <hip/hip_runtime.h>

#define NGRAPHS 2048
#define DIN     1536
#define DH1     64
#define DH2     32
#define TROWS   64      // rows per tile (power of 2; slot math uses >>6)
#define MAXSLOT 8       // max tiles a graph can span (max graph ~96 rows << 448)
#define MLPG    8       // graphs per finalize/MLP block

// ---------------- Pass 1: segment offsets (batch is sorted) ----------------
__global__ void find_offsets_kernel(const int* __restrict__ batch, int n,
                                    int* __restrict__ offsets) {
    int i = blockIdx.x * blockDim.x + threadIdx.x;
    if (i >= n) return;
    int b = batch[i];
    int prev = (i == 0) ? -1 : batch[i - 1];
    for (int g = prev + 1; g <= b; ++g) offsets[g] = i;
    if (i == n - 1) {
        for (int g = b + 1; g <= NGRAPHS; ++g) offsets[g] = n;
    }
}

// ---------------- Pass 2: perfectly balanced row-tile partial sums ----------
// Block t owns rows [64t, 64t+64): exactly 393KB of coalesced streaming per
// block -> no makespan imbalance. For each graph overlapping the tile, write
// the unnormalized partial sum to partial[g][t - first_tile(g)].
__global__ __launch_bounds__(384) void tile_sum_kernel(
    const float* __restrict__ features,
    const int* __restrict__ batch,
    const int* __restrict__ offsets,
    float* __restrict__ partial, int n)
{
    const int t    = blockIdx.x;
    const int tid  = threadIdx.x;
    const int R0   = t * TROWS;
    const int Rend = (R0 + TROWS < n) ? (R0 + TROWS) : n;
    if (R0 >= n) return;

    const int g0 = batch[R0];
    const int g1 = batch[Rend - 1];
    const float4* __restrict__ F4 = reinterpret_cast<const float4*>(features);

    for (int g = g0; g <= g1; ++g) {
        const int gs = offsets[g];
        const int ge = offsets[g + 1];
        const int s  = (gs > R0)   ? gs : R0;
        const int e  = (ge < Rend) ? ge : Rend;
        if (e <= s) continue;                    // graph empty inside this tile

        float4 a0 = make_float4(0.f, 0.f, 0.f, 0.f);
        float4 a1 = make_float4(0.f, 0.f, 0.f, 0.f);
        float4 a2 = make_float4(0.f, 0.f, 0.f, 0.f);
        float4 a3 = make_float4(0.f, 0.f, 0.f, 0.f);
        int r = s;
        for (; r + 4 <= e; r += 4) {
            float4 v0 = F4[(size_t)(r + 0) * (DIN / 4) + tid];
            float4 v1 = F4[(size_t)(r + 1) * (DIN / 4) + tid];
            float4 v2 = F4[(size_t)(r + 2) * (DIN / 4) + tid];
            float4 v3 = F4[(size_t)(r + 3) * (DIN / 4) + tid];
            a0.x += v0.x; a0.y += v0.y; a0.z += v0.z; a0.w += v0.w;
            a1.x += v1.x; a1.y += v1.y; a1.z += v1.z; a1.w += v1.w;
            a2.x += v2.x; a2.y += v2.y; a2.z += v2.z; a2.w += v2.w;
            a3.x += v3.x; a3.y += v3.y; a3.z += v3.z; a3.w += v3.w;
        }
        for (; r < e; ++r) {
            float4 v = F4[(size_t)r * (DIN / 4) + tid];
            a0.x += v.x; a0.y += v.y; a0.z += v.z; a0.w += v.w;
        }
        a0.x += a1.x + a2.x + a3.x;
        a0.y += a1.y + a2.y + a3.y;
        a0.z += a1.z + a2.z + a3.z;
        a0.w += a1.w + a2.w + a3.w;

        const int slot = t - (gs >> 6);          // 0..MAXSLOT-1
        reinterpret_cast<float4*>(
            partial + ((size_t)g * MAXSLOT + slot) * DIN)[tid] = a0;
    }
}

// ---------------- Pass 3: deterministic finalize + batched MLP --------------
// 256 blocks x 8 graphs. Sum each graph's partial slots in fixed tile order,
// divide by count -> LDS means -> MLP (W1 read 256x total, not 2048x).
__global__ __launch_bounds__(256) void finalize_mlp_kernel(
    const int* __restrict__ offsets,
    const float* __restrict__ partial,
    const float* __restrict__ W1, const float* __restrict__ b1,
    const float* __restrict__ W2, const float* __restrict__ b2,
    const float* __restrict__ W3, const float* __restrict__ b3,
    float* __restrict__ out)
{
    const int tid  = threadIdx.x;
    const int lane = tid & 63;
    const int bg   = blockIdx.x * MLPG;

    __shared__ float mean_s[MLPG][DIN];   // 48 KB
    __shared__ float h1_s[MLPG][DH1];
    __shared__ float h2_s[MLPG][DH2];

    // ---- reduce partial slots -> means (deterministic order) ----
    for (int gi = 0; gi < MLPG; ++gi) {
        const int g   = bg + gi;
        const int s   = offsets[g];
        const int e   = offsets[g + 1];
        const int cnt = e - s;
        const float inv  = (cnt > 0) ? 1.0f / (float)cnt : 0.0f;
        const int nslots = (cnt > 0) ? (((e - 1) >> 6) - (s >> 6) + 1) : 0;
        const float4* __restrict__ base =
            reinterpret_cast<const float4*>(partial + (size_t)g * MAXSLOT * DIN);
        float4* __restrict__ ms4 = reinterpret_cast<float4*>(mean_s[gi]);
        for (int c = tid; c < DIN / 4; c += 256) {
            float4 acc = make_float4(0.f, 0.f, 0.f, 0.f);
            for (int ss = 0; ss < nslots; ++ss) {
                float4 p = base[(size_t)ss * (DIN / 4) + c];
                acc.x += p.x; acc.y += p.y; acc.z += p.z; acc.w += p.w;
            }
            acc.x *= inv; acc.y *= inv; acc.z *= inv; acc.w *= inv;
            ms4[c] = acc;
        }
    }
    __syncthreads();

    // ---- layer 1: wave w -> graphs {2w,2w+1}; lane = output j ----
    {
        const int gpair = (tid >> 6) * 2;
        const float4* __restrict__ m0 =
            reinterpret_cast<const float4*>(mean_s[gpair]);
        const float4* __restrict__ m1 =
            reinterpret_cast<const float4*>(mean_s[gpair + 1]);
        const float4* __restrict__ w1r =
            reinterpret_cast<const float4*>(W1 + (size_t)lane * DIN);
        float a0 = 0.f, a1 = 0.f;
        #pragma unroll 8
        for (int k = 0; k < DIN / 4; ++k) {
            float4 wv = w1r[k];
            float4 u  = m0[k];           // LDS broadcast (same addr all lanes)
            float4 v  = m1[k];
            a0 += wv.x * u.x + wv.y * u.y + wv.z * u.z + wv.w * u.w;
            a1 += wv.x * v.x + wv.y * v.y + wv.z * v.z + wv.w * v.w;
        }
        const float bb = b1[lane];
        h1_s[gpair + 0][lane] = fmaxf(a0 + bb, 0.f);
        h1_s[gpair + 1][lane] = fmaxf(a1 + bb, 0.f);
    }
    __syncthreads();

    // ---- layer 2: 8 graphs x 32 outputs = 256 dots, one per thread ----
    {
        const int g = tid >> 5;
        const int j = tid & 31;
        const float* __restrict__ w2r = W2 + (size_t)j * DH1;
        float a = b2[j];
        #pragma unroll
        for (int k = 0; k < DH1; ++k) a += h1_s[g][k] * w2r[k];
        h2_s[g][j] = fmaxf(a, 0.f);
    }
    __syncthreads();

    // ---- layer 3 ----
    if (tid < MLPG) {
        float a = b3[0];
        #pragma unroll
        for (int j = 0; j < DH2; ++j) a += h2_s[tid][j] * W3[j];
        out[bg + tid] = a;
    }
}

// ---------------- Fallback: R2 fused kernel (if ws too small) ----------------
__global__ __launch_bounds__(384) void pool_mlp_fused_kernel(
    const float* __restrict__ features,
    const int* __restrict__ offsets,
    const float* __restrict__ W1, const float* __restrict__ b1,
    const float* __restrict__ W2, const float* __restrict__ b2,
    const float* __restrict__ W3, const float* __restrict__ b3,
    float* __restrict__ out)
{
    const int g    = blockIdx.x;
    const int tid  = threadIdx.x;
    const int lane = tid & 63;
    const int wave = tid >> 6;
    const int s = offsets[g];
    const int e = offsets[g + 1];

    __shared__ float mean_s[DIN];
    __shared__ float h1_s[DH1];
    __shared__ float h2_s[DH2];

    const float4* __restrict__ F4 = reinterpret_cast<const float4*>(features);
    float4 a0 = make_float4(0.f, 0.f, 0.f, 0.f);
    for (int r = s; r < e; ++r) {
        float4 v = F4[(size_t)r * (DIN / 4) + tid];
        a0.x += v.x; a0.y += v.y; a0.z += v.z; a0.w += v.w;
    }
    const int cnt = e - s;
    const float inv = 1.0f / (float)(cnt > 1 ? cnt : 1);
    a0.x *= inv; a0.y *= inv; a0.z *= inv; a0.w *= inv;
    reinterpret_cast<float4*>(mean_s)[tid] = a0;
    __syncthreads();

    const float4* __restrict__ m4 = reinterpret_cast<const float4*>(mean_s);
    for (int j = wave; j < DH1; j += 6) {
        const float4* __restrict__ w4 =
            reinterpret_cast<const float4*>(W1 + (size_t)j * DIN);
        float acc = 0.f;
        #pragma unroll
        for (int k = 0; k < DIN / 4 / 64; ++k) {
            float4 w = w4[k * 64 + lane];
            float4 m = m4[k * 64 + lane];
            acc += m.x * w.x + m.y * w.y + m.z * w.z + m.w * w.w;
        }
        #pragma unroll
        for (int off = 32; off; off >>= 1) acc += __shfl_xor(acc, off, 64);
        if (lane == 0) h1_s[j] = fmaxf(acc + b1[j], 0.f);
    }
    __syncthreads();

    for (int j = wave; j < DH2; j += 6) {
        float acc = h1_s[lane] * W2[(size_t)j * DH1 + lane];
        #pragma unroll
        for (int off = 32; off; off >>= 1) acc += __shfl_xor(acc, off, 64);
        if (lane == 0) h2_s[j] = fmaxf(acc + b2[j], 0.f);
    }
    __syncthreads();

    if (wave == 0) {
        float acc = (lane < DH2) ? h2_s[lane] * W3[lane] : 0.f;
        #pragma unroll
        for (int off = 32; off; off >>= 1) acc += __shfl_xor(acc, off, 64);
        if (lane == 0) out[g] = acc + b3[0];
    }
}

extern "C" void kernel_launch(void* const* d_in, const int* in_sizes, int n_in,
                              void* d_out, int out_size, void* d_ws, size_t ws_size,
                              hipStream_t stream) {
    const float* features = (const float*)d_in[0];
    const int*   batch    = (const int*)d_in[1];   // int64 in ref -> int32 (x64 off)
    const float* W1 = (const float*)d_in[2];
    const float* b1 = (const float*)d_in[3];
    const float* W2 = (const float*)d_in[4];
    const float* b2 = (const float*)d_in[5];
    const float* W3 = (const float*)d_in[6];
    const float* b3 = (const float*)d_in[7];
    float* out = (float*)d_out;

    const int n = in_sizes[1];                   // 131072 rows
    int* offsets = (int*)d_ws;                   // (NGRAPHS+1) ints
    const size_t part_off = 16384;
    float* partial = (float*)((char*)d_ws + part_off);
    const size_t need =
        part_off + (size_t)NGRAPHS * MAXSLOT * DIN * sizeof(float); // ~100.7 MB

    find_offsets_kernel<<<(n + 255) / 256, 256, 0, stream>>>(batch, n, offsets);

    if (ws_size >= need) {
        const int ntiles = (n + TROWS - 1) / TROWS;      // 2048
        tile_sum_kernel<<<ntiles, 384, 0, stream>>>(features, batch, offsets,
                                                    partial, n);
        finalize_mlp_kernel<<<NGRAPHS / MLPG, 256, 0, stream>>>(
            offsets, partial, W1, b1, W2, b2, W3, b3, out);
    } else {
        pool_mlp_fused_kernel<<<NGRAPHS, 384, 0, stream>>>(features, offsets,
                                                           W1, b1, W2, b2, W3, b3, out);
    }
}

// Round 7
// 163.378 us; speedup vs baseline: 1.4701x; 1.4701x over previous
//
#include <hip/hip_runtime.h>

#define NGRAPHS 2048
#define DIN     1536
#define DH1     64
#define DH2     32
#define POOL_BLOCKS 1280   // 5 blocks/CU x 256 CU — all co-resident, work-stealing

typedef float fvec4 __attribute__((ext_vector_type(4)));  // native vector: OK for nontemporal builtins

// ---------------- Pass 1: segment offsets (batch sorted) + zero counter -----
__global__ void find_offsets_kernel(const int* __restrict__ batch, int n,
                                    int* __restrict__ offsets,
                                    int* __restrict__ counter) {
    int i = blockIdx.x * blockDim.x + threadIdx.x;
    if (i == 0) *counter = 0;                      // reset work queue every call
    if (i >= n) return;
    int b = batch[i];
    int prev = (i == 0) ? -1 : batch[i - 1];
    for (int g = prev + 1; g <= b; ++g) offsets[g] = i;
    if (i == n - 1) {
        for (int g = b + 1; g <= NGRAPHS; ++g) offsets[g] = n;
    }
}

// ---------------- Pass 2: persistent fused pool+MLP with work-stealing ------
// 1280 blocks x 384 threads (6 waves). Each block repeatedly grabs the next
// graph id from a global counter: blocks that drew small graphs grab more, so
// finish times equalize (kills the makespan tail of static 1-block-per-graph).
// Deterministic: each graph is computed wholly by one block with fixed math.
__global__ __launch_bounds__(384) void pool_mlp_ws_kernel(
    const float* __restrict__ features,
    const int* __restrict__ offsets,
    const float* __restrict__ W1, const float* __restrict__ b1,
    const float* __restrict__ W2, const float* __restrict__ b2,
    const float* __restrict__ W3, const float* __restrict__ b3,
    float* __restrict__ out,
    int* __restrict__ counter)
{
    const int tid  = threadIdx.x;
    const int lane = tid & 63;
    const int wave = tid >> 6;

    __shared__ float mean_s[DIN];
    __shared__ float h1_s[DH1];
    __shared__ float h2_s[DH2];
    __shared__ int   g_s;

    const fvec4* __restrict__ F4 = reinterpret_cast<const fvec4*>(features);

    for (;;) {
        if (tid == 0) g_s = atomicAdd(counter, 1);
        __syncthreads();
        const int g = g_s;
        if (g >= NGRAPHS) break;

        const int s = offsets[g];
        const int e = offsets[g + 1];

        // ---- segment sum: coalesced stream, x4 row unroll, nontemporal ----
        fvec4 a0 = (fvec4)(0.f);
        fvec4 a1 = (fvec4)(0.f);
        fvec4 a2 = (fvec4)(0.f);
        fvec4 a3 = (fvec4)(0.f);
        int r = s;
        for (; r + 4 <= e; r += 4) {
            fvec4 v0 = __builtin_nontemporal_load(&F4[(size_t)(r + 0) * (DIN / 4) + tid]);
            fvec4 v1 = __builtin_nontemporal_load(&F4[(size_t)(r + 1) * (DIN / 4) + tid]);
            fvec4 v2 = __builtin_nontemporal_load(&F4[(size_t)(r + 2) * (DIN / 4) + tid]);
            fvec4 v3 = __builtin_nontemporal_load(&F4[(size_t)(r + 3) * (DIN / 4) + tid]);
            a0 += v0; a1 += v1; a2 += v2; a3 += v3;
        }
        for (; r < e; ++r) {
            fvec4 v = __builtin_nontemporal_load(&F4[(size_t)r * (DIN / 4) + tid]);
            a0 += v;
        }
        a0 += a1 + a2 + a3;

        const int cnt = e - s;
        const float inv = 1.0f / (float)(cnt > 1 ? cnt : 1);
        a0 *= inv;
        reinterpret_cast<fvec4*>(mean_s)[tid] = a0;
        __syncthreads();

        // ---- layer 1: wave-cooperative, coalesced W1 (hot in L2) ----
        const fvec4* __restrict__ m4 = reinterpret_cast<const fvec4*>(mean_s);
        for (int j = wave; j < DH1; j += 6) {
            const fvec4* __restrict__ w4 =
                reinterpret_cast<const fvec4*>(W1 + (size_t)j * DIN);
            float acc = 0.f;
            #pragma unroll
            for (int k = 0; k < DIN / 4 / 64; ++k) {      // 6 iters
                fvec4 w = w4[k * 64 + lane];
                fvec4 m = m4[k * 64 + lane];
                acc += m.x * w.x + m.y * w.y + m.z * w.z + m.w * w.w;
            }
            #pragma unroll
            for (int off = 32; off; off >>= 1) acc += __shfl_xor(acc, off, 64);
            if (lane == 0) h1_s[j] = fmaxf(acc + b1[j], 0.f);
        }
        __syncthreads();

        // ---- layer 2 ----
        for (int j = wave; j < DH2; j += 6) {
            float acc = h1_s[lane] * W2[(size_t)j * DH1 + lane];
            #pragma unroll
            for (int off = 32; off; off >>= 1) acc += __shfl_xor(acc, off, 64);
            if (lane == 0) h2_s[j] = fmaxf(acc + b2[j], 0.f);
        }
        __syncthreads();

        // ---- layer 3 ----
        if (wave == 0) {
            float acc = (lane < DH2) ? h2_s[lane] * W3[lane] : 0.f;
            #pragma unroll
            for (int off = 32; off; off >>= 1) acc += __shfl_xor(acc, off, 64);
            if (lane == 0) out[g] = acc + b3[0];
        }
        __syncthreads();   // protect g_s / mean_s / h*_s before next grab
    }
}

extern "C" void kernel_launch(void* const* d_in, const int* in_sizes, int n_in,
                              void* d_out, int out_size, void* d_ws, size_t ws_size,
                              hipStream_t stream) {
    const float* features = (const float*)d_in[0];
    const int*   batch    = (const int*)d_in[1];   // int64 in ref -> int32 (x64 off)
    const float* W1 = (const float*)d_in[2];
    const float* b1 = (const float*)d_in[3];
    const float* W2 = (const float*)d_in[4];
    const float* b2 = (const float*)d_in[5];
    const float* W3 = (const float*)d_in[6];
    const float* b3 = (const float*)d_in[7];
    float* out = (float*)d_out;

    const int n = in_sizes[1];                 // 131072 rows
    int* counter = (int*)d_ws;                 // [0]: work-queue counter
    int* offsets = (int*)d_ws + 64;            // (NGRAPHS+1) ints, 256B-aligned

    find_offsets_kernel<<<(n + 255) / 256, 256, 0, stream>>>(batch, n, offsets,
                                                             counter);
    pool_mlp_ws_kernel<<<POOL_BLOCKS, 384, 0, stream>>>(features, offsets,
                                                        W1, b1, W2, b2, W3, b3,
                                                        out, counter);
}